// Round 2
// baseline (2378.354 us; speedup 1.0000x reference)
//
#include <hip/hip_runtime.h>
#include <cstdint>
#include <cstddef>

#define B_ 8
#define N_ 4096
#define C_ 768
#define H_ 8
#define HD_ 96
#define EPSN 1e-12f

// ---------------------------------------------------------------------------
// zero helper (avoid hipMemsetAsync during graph capture)
// ---------------------------------------------------------------------------
__global__ __launch_bounds__(256)
void zero_f4(float4* __restrict__ p, int n4) {
  const int i = blockIdx.x * 256 + threadIdx.x;
  if (i < n4) p[i] = make_float4(0.f, 0.f, 0.f, 0.f);
}

// ---------------------------------------------------------------------------
// Fused qk-projection + raw scores + norms. No q/k materialization.
// Block = (bh, 64-token tile). Phase 1: GEMM -> q,k tile (64 tok x 192 ch) in
// registers. Phase 2: via LDS, S[bh][d][e] += sum_t q[t][d]*k[t][e] (atomics),
// norms[q_d] += sum q^2, norms[k_e] += sum k^2.
// ---------------------------------------------------------------------------
__global__ __launch_bounds__(256)
void qk_scores(const float* __restrict__ x, const float* __restrict__ w_qkv,
               float* __restrict__ S, float* __restrict__ norms) {
  const int bh = blockIdx.x;
  const int b = bh >> 3, h = bh & 7;
  const int n0 = blockIdx.y * 64;
  const int tid = threadIdx.x;

  // smem: phase1 stage = xs[16][64] (1024) + wqk[16][192] (3072) = 4096 floats
  //       phase2 qkT[192][65] = 12480 floats (overlaps stage; sync between)
  __shared__ float smem[192 * 65];
  float* xs = smem;           // [k][tok]  k-major
  float* wqk = smem + 1024;   // [k][ch]

  const int ty = tid >> 4;        // token group: 4 tokens
  const int tx = tid & 15;        // channel group: 12 channels
  const int lr = tid >> 2;        // load row 0..63
  const int lk = (tid & 3) * 4;   // load k offset

  // global row in w_qkv for channel ch (0..191): q rows, then k rows
  float acc[4][12] = {};

  const float* xp = x + (size_t)(b * N_ + n0 + lr) * C_ + lk;

  for (int k0 = 0; k0 < C_; k0 += 16) {
    // fetch to registers
    const float4 xv = *(const float4*)(xp + k0);
    float4 wv[3];
#pragma unroll
    for (int j = 0; j < 3; ++j) {
      const int idx = tid + j * 256;          // 0..767 float4 slots
      const int r = idx >> 2;                 // channel 0..191
      const int kc = (idx & 3) * 4;
      const int grow = (r < 96) ? (h * 96 + r) : (2 * C_ / 2 /*768*/ + h * 96 + (r - 96));
      wv[j] = *(const float4*)(w_qkv + (size_t)grow * C_ + k0 + kc);
    }
    __syncthreads();
    // store stage: xs[k][tok], wqk[k][ch]
#pragma unroll
    for (int i = 0; i < 4; ++i) xs[(lk + i) * 64 + lr] = ((const float*)&xv)[i];
#pragma unroll
    for (int j = 0; j < 3; ++j) {
      const int idx = tid + j * 256;
      const int r = idx >> 2;
      const int kc = (idx & 3) * 4;
#pragma unroll
      for (int i = 0; i < 4; ++i) wqk[(kc + i) * 192 + r] = ((const float*)&wv[j])[i];
    }
    __syncthreads();
#pragma unroll
    for (int k = 0; k < 16; ++k) {
      const float4 a = *(const float4*)&xs[k * 64 + ty * 4];
      float bb[12];
#pragma unroll
      for (int j = 0; j < 3; ++j) {
        const float4 bv = *(const float4*)&wqk[k * 192 + tx * 12 + j * 4];
        bb[j * 4 + 0] = bv.x; bb[j * 4 + 1] = bv.y; bb[j * 4 + 2] = bv.z; bb[j * 4 + 3] = bv.w;
      }
#pragma unroll
      for (int t = 0; t < 4; ++t) {
        const float av = ((const float*)&a)[t];
#pragma unroll
        for (int j = 0; j < 12; ++j) acc[t][j] += av * bb[j];
      }
    }
  }

  // phase 2: write q,k tile to LDS as qkT[ch][tok], pad 65
  __syncthreads();
#pragma unroll
  for (int t = 0; t < 4; ++t)
#pragma unroll
    for (int j = 0; j < 12; ++j)
      smem[(tx * 12 + j) * 65 + ty * 4 + t] = acc[t][j];
  __syncthreads();

  // norms
  if (tid < 192) {
    float s = 0.f;
    const float* row = &smem[tid * 65];
#pragma unroll 8
    for (int t = 0; t < 64; ++t) { const float v = row[t]; s += v * v; }
    if (tid < 96) atomicAdd(&norms[bh * 96 + tid], s);
    else atomicAdd(&norms[B_ * H_ * 96 + bh * 96 + (tid - 96)], s);
  }

  // scores: 16x16 threads, 6x6 each
  const int d0 = (tid & 15) * 6;
  const int e0 = (tid >> 4) * 6;
  float sc[6][6] = {};
  for (int t = 0; t < 64; ++t) {
    float qa[6], kb[6];
#pragma unroll
    for (int i = 0; i < 6; ++i) qa[i] = smem[(d0 + i) * 65 + t];
#pragma unroll
    for (int j = 0; j < 6; ++j) kb[j] = smem[(96 + e0 + j) * 65 + t];
#pragma unroll
    for (int i = 0; i < 6; ++i)
#pragma unroll
      for (int j = 0; j < 6; ++j) sc[i][j] += qa[i] * kb[j];
  }
  float* Sb = S + (size_t)bh * (HD_ * HD_);
#pragma unroll
  for (int i = 0; i < 6; ++i)
#pragma unroll
    for (int j = 0; j < 6; ++j)
      atomicAdd(&Sb[(d0 + i) * HD_ + (e0 + j)], sc[i][j]);
}

// ---------------------------------------------------------------------------
// softmax over e with l2-norm scaling and temperature. One wave per row.
// ---------------------------------------------------------------------------
__global__ __launch_bounds__(256)
void softmax_rows(float* __restrict__ S, const float* __restrict__ norms,
                  const float* __restrict__ temp) {
  const int row = blockIdx.x * 4 + (threadIdx.x >> 6);  // = bh*96 + d
  const int lane = threadIdx.x & 63;
  const int bh = row / 96;
  const int h = bh & 7;
  const float sq = 1.0f / fmaxf(sqrtf(norms[row]), EPSN);
  const float t = temp[h];
  const float* nkb = norms + B_ * H_ * 96 + bh * 96;
  float* r = S + (size_t)row * 96;
  const float f = sq * t;
  float v0 = r[lane] * f / fmaxf(sqrtf(nkb[lane]), EPSN);
  float v1 = -1e30f;
  if (lane < 32) v1 = r[64 + lane] * f / fmaxf(sqrtf(nkb[64 + lane]), EPSN);
  float m = fmaxf(v0, v1);
#pragma unroll
  for (int o = 32; o > 0; o >>= 1) m = fmaxf(m, __shfl_xor(m, o));
  const float e0 = __expf(v0 - m);
  const float e1 = (lane < 32) ? __expf(v1 - m) : 0.0f;
  float s = e0 + e1;
#pragma unroll
  for (int o = 32; o > 0; o >>= 1) s += __shfl_xor(s, o);
  const float inv = 1.0f / s;
  r[lane] = e0 * inv;
  if (lane < 32) r[64 + lane] = e1 * inv;
}

// ---------------------------------------------------------------------------
// AV_b[h*96+d][c] = sum_e attn[bh][d][e] * w_qkv[2C + h*96 + e][c]
// grid (B*H, C/64). LDS: attn 96x97 + wv 96x64.
// ---------------------------------------------------------------------------
__global__ __launch_bounds__(256)
void av_gemm(const float* __restrict__ S, const float* __restrict__ w_qkv,
             float* __restrict__ AV) {
  const int bh = blockIdx.x;
  const int b = bh >> 3, h = bh & 7;
  const int ct = blockIdx.y * 64;
  const int tid = threadIdx.x;
  __shared__ float at[96 * 97];
  __shared__ float wv[96 * 64];
  const float* Sb = S + (size_t)bh * (HD_ * HD_);
  for (int i = tid; i < 96 * 96; i += 256)
    at[(i / 96) * 97 + (i % 96)] = Sb[i];
  for (int i = tid; i < 96 * 64; i += 256) {
    const int e = i >> 6, c = i & 63;
    wv[e * 64 + c] = w_qkv[(size_t)(2 * C_ + h * 96 + e) * C_ + ct + c];
  }
  __syncthreads();
  const int d0 = (tid >> 4) * 6;
  const int c0 = (tid & 15) * 4;
  float acc[6][4] = {};
  for (int e = 0; e < 96; ++e) {
    const float4 bv = *(const float4*)&wv[e * 64 + c0];
    float aa[6];
#pragma unroll
    for (int i = 0; i < 6; ++i) aa[i] = at[(d0 + i) * 97 + e];
#pragma unroll
    for (int i = 0; i < 6; ++i) {
      acc[i][0] += aa[i] * bv.x; acc[i][1] += aa[i] * bv.y;
      acc[i][2] += aa[i] * bv.z; acc[i][3] += aa[i] * bv.w;
    }
  }
  float* AVb = AV + (size_t)b * C_ * C_;
#pragma unroll
  for (int i = 0; i < 6; ++i)
    *(float4*)&AVb[(size_t)(h * 96 + d0 + i) * C_ + ct + c0] =
        make_float4(acc[i][0], acc[i][1], acc[i][2], acc[i][3]);
}

// ---------------------------------------------------------------------------
// NN GEMM: C[m][n] = sum_k A[m][k] * B[k][n], per-z strides. 64x64 tile BK=16.
// ---------------------------------------------------------------------------
__global__ __launch_bounds__(256)
void gemm_nn(const float* __restrict__ A, const float* __restrict__ B,
             float* __restrict__ C, int M, int N, int K,
             size_t sA, size_t sB, size_t sC) {
  const int z = blockIdx.z;
  A += z * sA; B += z * sB; C += z * sC;
  __shared__ float As[16 * 64];   // [k][m]
  __shared__ float Bs[16 * 64];   // [k][n]
  const int tid = threadIdx.x;
  const int bm = blockIdx.y * 64;
  const int bn = blockIdx.x * 64;
  const int tx = tid & 15;
  const int ty = tid >> 4;
  const int lr = tid >> 2;        // A row
  const int lk = (tid & 3) * 4;   // A k-offset
  const int bkr = tid >> 4;       // B k-row
  const int bnc = (tid & 15) * 4; // B n-offset
  float acc[4][4] = {};
  for (int k0 = 0; k0 < K; k0 += 16) {
    const float4 av = *(const float4*)(A + (size_t)(bm + lr) * K + k0 + lk);
    const float4 bv = *(const float4*)(B + (size_t)(k0 + bkr) * N + bn + bnc);
    __syncthreads();
#pragma unroll
    for (int i = 0; i < 4; ++i) As[(lk + i) * 64 + lr] = ((const float*)&av)[i];
    *(float4*)&Bs[bkr * 64 + bnc] = bv;
    __syncthreads();
#pragma unroll
    for (int k = 0; k < 16; ++k) {
      const float4 a = *(const float4*)&As[k * 64 + ty * 4];
      const float4 b = *(const float4*)&Bs[k * 64 + tx * 4];
      acc[0][0] += a.x*b.x; acc[0][1] += a.x*b.y; acc[0][2] += a.x*b.z; acc[0][3] += a.x*b.w;
      acc[1][0] += a.y*b.x; acc[1][1] += a.y*b.y; acc[1][2] += a.y*b.z; acc[1][3] += a.y*b.w;
      acc[2][0] += a.z*b.x; acc[2][1] += a.z*b.y; acc[2][2] += a.z*b.z; acc[2][3] += a.z*b.w;
      acc[3][0] += a.w*b.x; acc[3][1] += a.w*b.y; acc[3][2] += a.w*b.z; acc[3][3] += a.w*b.w;
    }
  }
#pragma unroll
  for (int i = 0; i < 4; ++i)
    *(float4*)&C[(size_t)(bm + ty * 4 + i) * N + bn + tx * 4] =
        make_float4(acc[i][0], acc[i][1], acc[i][2], acc[i][3]);
}

// ---------------------------------------------------------------------------
// NT GEMM with bias + per-z strides: C[m][n] = sum_k A[m][k]*Bw[n][k] + bias[n]
// ---------------------------------------------------------------------------
__global__ __launch_bounds__(256)
void gemm_bt(const float* __restrict__ A, const float* __restrict__ Bw,
             const float* __restrict__ bias, float* __restrict__ C,
             int M, int N, int K, size_t sA, size_t sB, size_t sC) {
  const int z = blockIdx.z;
  A += z * sA; Bw += z * sB; C += z * sC;
  __shared__ float As[16 * 64];
  __shared__ float Bs[16 * 64];
  const int tid = threadIdx.x;
  const int bm = blockIdx.y * 64;
  const int bn = blockIdx.x * 64;
  const int tx = tid & 15;
  const int ty = tid >> 4;
  const int lr = tid >> 2;
  const int lk = (tid & 3) * 4;
  const float* Ap = A + (size_t)(bm + lr) * K + lk;
  const float* Bp = Bw + (size_t)(bn + lr) * K + lk;
  float acc[4][4] = {};
  for (int k0 = 0; k0 < K; k0 += 16) {
    const float4 av = *(const float4*)(Ap + k0);
    const float4 bv = *(const float4*)(Bp + k0);
    __syncthreads();
#pragma unroll
    for (int i = 0; i < 4; ++i) As[(lk + i) * 64 + lr] = ((const float*)&av)[i];
#pragma unroll
    for (int i = 0; i < 4; ++i) Bs[(lk + i) * 64 + lr] = ((const float*)&bv)[i];
    __syncthreads();
#pragma unroll
    for (int k = 0; k < 16; ++k) {
      const float4 a = *(const float4*)&As[k * 64 + ty * 4];
      const float4 b = *(const float4*)&Bs[k * 64 + tx * 4];
      acc[0][0] += a.x*b.x; acc[0][1] += a.x*b.y; acc[0][2] += a.x*b.z; acc[0][3] += a.x*b.w;
      acc[1][0] += a.y*b.x; acc[1][1] += a.y*b.y; acc[1][2] += a.y*b.z; acc[1][3] += a.y*b.w;
      acc[2][0] += a.z*b.x; acc[2][1] += a.z*b.y; acc[2][2] += a.z*b.z; acc[2][3] += a.z*b.w;
      acc[3][0] += a.w*b.x; acc[3][1] += a.w*b.y; acc[3][2] += a.w*b.z; acc[3][3] += a.w*b.w;
    }
  }
#pragma unroll
  for (int i = 0; i < 4; ++i) {
    float4 r = make_float4(acc[i][0], acc[i][1], acc[i][2], acc[i][3]);
    r.x += bias[bn + tx * 4 + 0];
    r.y += bias[bn + tx * 4 + 1];
    r.z += bias[bn + tx * 4 + 2];
    r.w += bias[bn + tx * 4 + 3];
    *(float4*)&C[(size_t)(bm + ty * 4 + i) * N + bn + tx * 4] = r;
  }
}

// ---------------------------------------------------------------------------
extern "C" void kernel_launch(void* const* d_in, const int* in_sizes, int n_in,
                              void* d_out, int out_size, void* d_ws, size_t ws_size,
                              hipStream_t stream) {
  const float* x      = (const float*)d_in[0];
  const float* w_qkv  = (const float*)d_in[1];
  const float* temp   = (const float*)d_in[2];
  const float* w_proj = (const float*)d_in[3];
  const float* b_proj = (const float*)d_in[4];
  float* out = (float*)d_out;

  float* ws    = (float*)d_ws;
  float* S     = ws;                                       // B*H*96*96 = 589824
  float* norms = S + (size_t)B_ * H_ * HD_ * HD_;          // 2*B*H*96  = 12288
  float* AV    = norms + 2 * B_ * H_ * HD_;                // 8*768*768 = 4718592
  float* M     = AV + (size_t)B_ * C_ * C_;                // 8*768*768 = 4718592
  // total: 10,039,296 floats = 40.2 MB

  // zero S + norms (contiguous, 602112 floats = 150528 float4)
  zero_f4<<<588, 256, 0, stream>>>((float4*)S, 150528);

  // fused qk projection + scores + norms
  qk_scores<<<dim3(B_ * H_, N_ / 64), 256, 0, stream>>>(x, w_qkv, S, norms);

  // scaled softmax
  softmax_rows<<<(B_ * H_ * HD_) / 4, 256, 0, stream>>>(S, norms, temp);

  // AV_b = blockdiag(attn) @ W_v
  av_gemm<<<dim3(B_ * H_, C_ / 64), 256, 0, stream>>>(S, w_qkv, AV);

  // M_b = w_proj @ AV_b   (NN, batched over z)
  gemm_nn<<<dim3(C_ / 64, C_ / 64, B_), 256, 0, stream>>>(
      w_proj, AV, M, C_, C_, C_, 0, (size_t)C_ * C_, (size_t)C_ * C_);

  // out[b] = x[b] @ M_b^T + b_proj   (NT, batched over z)
  gemm_bt<<<dim3(C_ / 64, N_ / 64, B_), 256, 0, stream>>>(
      x, M, b_proj, out, N_, C_, C_, (size_t)N_ * C_, (size_t)C_ * C_,
      (size_t)N_ * C_);
}

// Round 3
// 1157.268 us; speedup vs baseline: 2.0551x; 2.0551x over previous
//
#include <hip/hip_runtime.h>
#include <cstdint>
#include <cstddef>

#define B_ 8
#define N_ 4096
#define C_ 768
#define H_ 8
#define HD_ 96
#define EPSN 1e-12f

typedef short s16x8 __attribute__((ext_vector_type(8)));   // 8 bf16 (4 VGPRs)
typedef float f32x4 __attribute__((ext_vector_type(4)));   // MFMA acc

// fp32 -> bf16 (RNE) as raw short bits
static __device__ __forceinline__ short f2bf(float f) {
  unsigned u = __float_as_uint(f);
  unsigned r = (u + 0x7fff + ((u >> 16) & 1)) >> 16;
  return (short)r;
}
static __device__ __forceinline__ float bf2f(unsigned short s) {
  return __uint_as_float(((unsigned)s) << 16);
}
static __device__ __forceinline__ s16x8 pack8(const float4 a, const float4 b) {
  s16x8 r;
  r[0] = f2bf(a.x); r[1] = f2bf(a.y); r[2] = f2bf(a.z); r[3] = f2bf(a.w);
  r[4] = f2bf(b.x); r[5] = f2bf(b.y); r[6] = f2bf(b.z); r[7] = f2bf(b.w);
  return r;
}

// ---------------------------------------------------------------------------
__global__ __launch_bounds__(256)
void zero_f4(float4* __restrict__ p, int n4) {
  const int i = blockIdx.x * 256 + threadIdx.x;
  if (i < n4) p[i] = make_float4(0.f, 0.f, 0.f, 0.f);
}

// ---------------------------------------------------------------------------
// Fused qk-projection + raw scores + norms, bf16 MFMA version.
// Block = (bh, 64-token tile), 256 threads (4 waves, wave grid 2x2).
// Phase 1: out[64 tok][192 ch] = x_tile @ Wqk_head^T via 16x16x32 bf16 MFMA,
//          K-chunks of 64 staged fp32->bf16 into LDS (stride 72 = 2-way only).
// Phase 2: acc -> qkT[ch][tok] bf16 in LDS; norms; S += qT k via MFMA; atomics.
// ---------------------------------------------------------------------------
__global__ __launch_bounds__(256)
void qk_scores(const float* __restrict__ x, const float* __restrict__ w_qkv,
               float* __restrict__ S, float* __restrict__ norms) {
  const int bh = blockIdx.x;
  const int b = bh >> 3, h = bh & 7;
  const int n0 = blockIdx.y * 64;
  const int tid = threadIdx.x;
  const int lane = tid & 63;
  const int wave = tid >> 6;
  const int l15 = lane & 15;
  const int quad = lane >> 4;
  const int wave_m = wave & 1;   // token-half (32 rows)
  const int wave_n = wave >> 1;  // channel-half (96 cols)

  // LDS: phase1 xs[64][72] + ws[192][72] bf16 = 36864 B; phase2 qkT[192][72]
  __shared__ __align__(16) short smem[18432];
  short* xs  = smem;          // 64*72 = 4608
  short* wsh = smem + 4608;   // 192*72 = 13824
  short* qkT = smem;          // alias (phase 2)

  // staging maps
  const int xr = tid >> 2;            // token row 0..63
  const int xc = (tid & 3) * 16;      // k offset within chunk
  const float* xp = x + (size_t)(b * N_ + n0 + xr) * C_ + xc;
  const float* wp[3];
  int wrow[3];
#pragma unroll
  for (int j = 0; j < 3; ++j) {
    const int id = tid + j * 256;     // 0..767
    const int r = id >> 2;            // channel 0..191
    wrow[j] = r;
    const int grow = (r < 96) ? (h * 96 + r) : (C_ + h * 96 + (r - 96));
    wp[j] = w_qkv + (size_t)grow * C_ + (id & 3) * 16;
  }

  f32x4 acc[2][6] = {};

  for (int k0 = 0; k0 < C_; k0 += 64) {
    // fetch fp32
    float4 xv0 = *(const float4*)(xp + k0 + 0);
    float4 xv1 = *(const float4*)(xp + k0 + 4);
    float4 xv2 = *(const float4*)(xp + k0 + 8);
    float4 xv3 = *(const float4*)(xp + k0 + 12);
    float4 wv[3][4];
#pragma unroll
    for (int j = 0; j < 3; ++j)
#pragma unroll
      for (int i = 0; i < 4; ++i)
        wv[j][i] = *(const float4*)(wp[j] + k0 + i * 4);
    __syncthreads();
    *(s16x8*)&xs[xr * 72 + xc]     = pack8(xv0, xv1);
    *(s16x8*)&xs[xr * 72 + xc + 8] = pack8(xv2, xv3);
#pragma unroll
    for (int j = 0; j < 3; ++j) {
      const int id = tid + j * 256;
      const int seg = (id & 3) * 16;
      *(s16x8*)&wsh[wrow[j] * 72 + seg]     = pack8(wv[j][0], wv[j][1]);
      *(s16x8*)&wsh[wrow[j] * 72 + seg + 8] = pack8(wv[j][2], wv[j][3]);
    }
    __syncthreads();
#pragma unroll
    for (int ks = 0; ks < 64; ks += 32) {
      s16x8 af[2];
#pragma unroll
      for (int mi = 0; mi < 2; ++mi)
        af[mi] = *(const s16x8*)&xs[(wave_m * 32 + mi * 16 + l15) * 72 + ks + quad * 8];
#pragma unroll
      for (int ni = 0; ni < 6; ++ni) {
        const s16x8 bf = *(const s16x8*)&wsh[(wave_n * 96 + ni * 16 + l15) * 72 + ks + quad * 8];
#pragma unroll
        for (int mi = 0; mi < 2; ++mi)
          acc[mi][ni] = __builtin_amdgcn_mfma_f32_16x16x32_bf16(af[mi], bf, acc[mi][ni], 0, 0, 0);
      }
    }
  }

  // phase 2: acc (C-layout: col=lane&15 -> channel, row=quad*4+reg -> token)
  // write to qkT[ch][tok], bf16, stride 72
  __syncthreads();
#pragma unroll
  for (int mi = 0; mi < 2; ++mi)
#pragma unroll
    for (int ni = 0; ni < 6; ++ni) {
      const int ch = wave_n * 96 + ni * 16 + l15;
      const int tok = wave_m * 32 + mi * 16 + quad * 4;
#pragma unroll
      for (int r = 0; r < 4; ++r)
        qkT[ch * 72 + tok + r] = f2bf(acc[mi][ni][r]);
    }
  __syncthreads();

  // norms (from bf16 tile)
  if (tid < 192) {
    float s = 0.f;
    const short* row = &qkT[tid * 72];
#pragma unroll 8
    for (int t = 0; t < 64; ++t) { const float v = bf2f((unsigned short)row[t]); s += v * v; }
    if (tid < 96) atomicAdd(&norms[bh * 96 + tid], s);
    else atomicAdd(&norms[B_ * H_ * 96 + bh * 96 + (tid - 96)], s);
  }

  // scores: S[d][e] += sum_t q[t][d]*k[t][e]; 36 16x16 tiles, 9 per wave, K=64
  float* Sb = S + (size_t)bh * (HD_ * HD_);
#pragma unroll
  for (int j = 0; j < 9; ++j) {
    const int t = wave * 9 + j;
    const int dt = t / 6, et = t % 6;
    f32x4 sc = {};
#pragma unroll
    for (int ks = 0; ks < 64; ks += 32) {
      const s16x8 a = *(const s16x8*)&qkT[(dt * 16 + l15) * 72 + ks + quad * 8];
      const s16x8 bb = *(const s16x8*)&qkT[(96 + et * 16 + l15) * 72 + ks + quad * 8];
      sc = __builtin_amdgcn_mfma_f32_16x16x32_bf16(a, bb, sc, 0, 0, 0);
    }
    const int d0 = dt * 16 + quad * 4;
    const int e = et * 16 + l15;
#pragma unroll
    for (int r = 0; r < 4; ++r)
      atomicAdd(&Sb[(d0 + r) * HD_ + e], sc[r]);
  }
}

// ---------------------------------------------------------------------------
// softmax over e with l2-norm scaling and temperature. One wave per row.
// ---------------------------------------------------------------------------
__global__ __launch_bounds__(256)
void softmax_rows(float* __restrict__ S, const float* __restrict__ norms,
                  const float* __restrict__ temp) {
  const int row = blockIdx.x * 4 + (threadIdx.x >> 6);  // = bh*96 + d
  const int lane = threadIdx.x & 63;
  const int bh = row / 96;
  const int h = bh & 7;
  const float sq = 1.0f / fmaxf(sqrtf(norms[row]), EPSN);
  const float t = temp[h];
  const float* nkb = norms + B_ * H_ * 96 + bh * 96;
  float* r = S + (size_t)row * 96;
  const float f = sq * t;
  float v0 = r[lane] * f / fmaxf(sqrtf(nkb[lane]), EPSN);
  float v1 = -1e30f;
  if (lane < 32) v1 = r[64 + lane] * f / fmaxf(sqrtf(nkb[64 + lane]), EPSN);
  float m = fmaxf(v0, v1);
#pragma unroll
  for (int o = 32; o > 0; o >>= 1) m = fmaxf(m, __shfl_xor(m, o));
  const float e0 = __expf(v0 - m);
  const float e1 = (lane < 32) ? __expf(v1 - m) : 0.0f;
  float s = e0 + e1;
#pragma unroll
  for (int o = 32; o > 0; o >>= 1) s += __shfl_xor(s, o);
  const float inv = 1.0f / s;
  r[lane] = e0 * inv;
  if (lane < 32) r[64 + lane] = e1 * inv;
}

// ---------------------------------------------------------------------------
// AV_b[h*96+d][c] = sum_e attn[bh][d][e] * w_qkv[2C + h*96 + e][c]
// ---------------------------------------------------------------------------
__global__ __launch_bounds__(256)
void av_gemm(const float* __restrict__ S, const float* __restrict__ w_qkv,
             float* __restrict__ AV) {
  const int bh = blockIdx.x;
  const int b = bh >> 3, h = bh & 7;
  const int ct = blockIdx.y * 64;
  const int tid = threadIdx.x;
  __shared__ float at[96 * 97];
  __shared__ float wv[96 * 64];
  const float* Sb = S + (size_t)bh * (HD_ * HD_);
  for (int i = tid; i < 96 * 96; i += 256)
    at[(i / 96) * 97 + (i % 96)] = Sb[i];
  for (int i = tid; i < 96 * 64; i += 256) {
    const int e = i >> 6, c = i & 63;
    wv[e * 64 + c] = w_qkv[(size_t)(2 * C_ + h * 96 + e) * C_ + ct + c];
  }
  __syncthreads();
  const int d0 = (tid >> 4) * 6;
  const int c0 = (tid & 15) * 4;
  float acc[6][4] = {};
  for (int e = 0; e < 96; ++e) {
    const float4 bv = *(const float4*)&wv[e * 64 + c0];
    float aa[6];
#pragma unroll
    for (int i = 0; i < 6; ++i) aa[i] = at[(d0 + i) * 97 + e];
#pragma unroll
    for (int i = 0; i < 6; ++i) {
      acc[i][0] += aa[i] * bv.x; acc[i][1] += aa[i] * bv.y;
      acc[i][2] += aa[i] * bv.z; acc[i][3] += aa[i] * bv.w;
    }
  }
  float* AVb = AV + (size_t)b * C_ * C_;
#pragma unroll
  for (int i = 0; i < 6; ++i)
    *(float4*)&AVb[(size_t)(h * 96 + d0 + i) * C_ + ct + c0] =
        make_float4(acc[i][0], acc[i][1], acc[i][2], acc[i][3]);
}

// ---------------------------------------------------------------------------
// NN GEMM: C[m][n] = sum_k A[m][k] * B[k][n], per-z strides. 64x64 tile BK=16.
// ---------------------------------------------------------------------------
__global__ __launch_bounds__(256)
void gemm_nn(const float* __restrict__ A, const float* __restrict__ B,
             float* __restrict__ C, int M, int N, int K,
             size_t sA, size_t sB, size_t sC) {
  const int z = blockIdx.z;
  A += z * sA; B += z * sB; C += z * sC;
  __shared__ float As[16 * 64];
  __shared__ float Bs[16 * 64];
  const int tid = threadIdx.x;
  const int bm = blockIdx.y * 64;
  const int bn = blockIdx.x * 64;
  const int tx = tid & 15;
  const int ty = tid >> 4;
  const int lr = tid >> 2;
  const int lk = (tid & 3) * 4;
  const int bkr = tid >> 4;
  const int bnc = (tid & 15) * 4;
  float acc[4][4] = {};
  for (int k0 = 0; k0 < K; k0 += 16) {
    const float4 av = *(const float4*)(A + (size_t)(bm + lr) * K + k0 + lk);
    const float4 bv = *(const float4*)(B + (size_t)(k0 + bkr) * N + bn + bnc);
    __syncthreads();
#pragma unroll
    for (int i = 0; i < 4; ++i) As[(lk + i) * 64 + lr] = ((const float*)&av)[i];
    *(float4*)&Bs[bkr * 64 + bnc] = bv;
    __syncthreads();
#pragma unroll
    for (int k = 0; k < 16; ++k) {
      const float4 a = *(const float4*)&As[k * 64 + ty * 4];
      const float4 b = *(const float4*)&Bs[k * 64 + tx * 4];
      acc[0][0] += a.x*b.x; acc[0][1] += a.x*b.y; acc[0][2] += a.x*b.z; acc[0][3] += a.x*b.w;
      acc[1][0] += a.y*b.x; acc[1][1] += a.y*b.y; acc[1][2] += a.y*b.z; acc[1][3] += a.y*b.w;
      acc[2][0] += a.z*b.x; acc[2][1] += a.z*b.y; acc[2][2] += a.z*b.z; acc[2][3] += a.z*b.w;
      acc[3][0] += a.w*b.x; acc[3][1] += a.w*b.y; acc[3][2] += a.w*b.z; acc[3][3] += a.w*b.w;
    }
  }
#pragma unroll
  for (int i = 0; i < 4; ++i)
    *(float4*)&C[(size_t)(bm + ty * 4 + i) * N + bn + tx * 4] =
        make_float4(acc[i][0], acc[i][1], acc[i][2], acc[i][3]);
}

// ---------------------------------------------------------------------------
// NT GEMM with bias + per-z strides: C[m][n] = sum_k A[m][k]*Bw[n][k] + bias[n]
// ---------------------------------------------------------------------------
__global__ __launch_bounds__(256)
void gemm_bt(const float* __restrict__ A, const float* __restrict__ Bw,
             const float* __restrict__ bias, float* __restrict__ C,
             int M, int N, int K, size_t sA, size_t sB, size_t sC) {
  const int z = blockIdx.z;
  A += z * sA; Bw += z * sB; C += z * sC;
  __shared__ float As[16 * 64];
  __shared__ float Bs[16 * 64];
  const int tid = threadIdx.x;
  const int bm = blockIdx.y * 64;
  const int bn = blockIdx.x * 64;
  const int tx = tid & 15;
  const int ty = tid >> 4;
  const int lr = tid >> 2;
  const int lk = (tid & 3) * 4;
  const float* Ap = A + (size_t)(bm + lr) * K + lk;
  const float* Bp = Bw + (size_t)(bn + lr) * K + lk;
  float acc[4][4] = {};
  for (int k0 = 0; k0 < K; k0 += 16) {
    const float4 av = *(const float4*)(Ap + k0);
    const float4 bv = *(const float4*)(Bp + k0);
    __syncthreads();
#pragma unroll
    for (int i = 0; i < 4; ++i) As[(lk + i) * 64 + lr] = ((const float*)&av)[i];
#pragma unroll
    for (int i = 0; i < 4; ++i) Bs[(lk + i) * 64 + lr] = ((const float*)&bv)[i];
    __syncthreads();
#pragma unroll
    for (int k = 0; k < 16; ++k) {
      const float4 a = *(const float4*)&As[k * 64 + ty * 4];
      const float4 b = *(const float4*)&Bs[k * 64 + tx * 4];
      acc[0][0] += a.x*b.x; acc[0][1] += a.x*b.y; acc[0][2] += a.x*b.z; acc[0][3] += a.x*b.w;
      acc[1][0] += a.y*b.x; acc[1][1] += a.y*b.y; acc[1][2] += a.y*b.z; acc[1][3] += a.y*b.w;
      acc[2][0] += a.z*b.x; acc[2][1] += a.z*b.y; acc[2][2] += a.z*b.z; acc[2][3] += a.z*b.w;
      acc[3][0] += a.w*b.x; acc[3][1] += a.w*b.y; acc[3][2] += a.w*b.z; acc[3][3] += a.w*b.w;
    }
  }
#pragma unroll
  for (int i = 0; i < 4; ++i) {
    float4 r = make_float4(acc[i][0], acc[i][1], acc[i][2], acc[i][3]);
    r.x += bias[bn + tx * 4 + 0];
    r.y += bias[bn + tx * 4 + 1];
    r.z += bias[bn + tx * 4 + 2];
    r.w += bias[bn + tx * 4 + 3];
    *(float4*)&C[(size_t)(bm + ty * 4 + i) * N + bn + tx * 4] = r;
  }
}

// ---------------------------------------------------------------------------
extern "C" void kernel_launch(void* const* d_in, const int* in_sizes, int n_in,
                              void* d_out, int out_size, void* d_ws, size_t ws_size,
                              hipStream_t stream) {
  const float* x      = (const float*)d_in[0];
  const float* w_qkv  = (const float*)d_in[1];
  const float* temp   = (const float*)d_in[2];
  const float* w_proj = (const float*)d_in[3];
  const float* b_proj = (const float*)d_in[4];
  float* out = (float*)d_out;

  float* ws    = (float*)d_ws;
  float* S     = ws;                                       // B*H*96*96 = 589824
  float* norms = S + (size_t)B_ * H_ * HD_ * HD_;          // 2*B*H*96  = 12288
  float* AV    = norms + 2 * B_ * H_ * HD_;                // 8*768*768
  float* M     = AV + (size_t)B_ * C_ * C_;                // 8*768*768
  // total ~40.2 MB

  zero_f4<<<588, 256, 0, stream>>>((float4*)S, 150528);

  qk_scores<<<dim3(B_ * H_, N_ / 64), 256, 0, stream>>>(x, w_qkv, S, norms);

  softmax_rows<<<(B_ * H_ * HD_) / 4, 256, 0, stream>>>(S, norms, temp);

  av_gemm<<<dim3(B_ * H_, C_ / 64), 256, 0, stream>>>(S, w_qkv, AV);

  gemm_nn<<<dim3(C_ / 64, C_ / 64, B_), 256, 0, stream>>>(
      w_proj, AV, M, C_, C_, C_, 0, (size_t)C_ * C_, (size_t)C_ * C_);

  gemm_bt<<<dim3(C_ / 64, N_ / 64, B_), 256, 0, stream>>>(
      x, M, b_proj, out, N_, C_, C_, (size_t)N_ * C_, (size_t)C_ * C_,
      (size_t)N_ * C_);
}

// Round 4
// 686.048 us; speedup vs baseline: 3.4667x; 1.6869x over previous
//
#include <hip/hip_runtime.h>
#include <cstdint>
#include <cstddef>

#define B_ 8
#define N_ 4096
#define C_ 768
#define H_ 8
#define HD_ 96
#define EPSN 1e-12f

typedef short s16x8 __attribute__((ext_vector_type(8)));   // 8 bf16 (4 VGPRs)
typedef short s16x4 __attribute__((ext_vector_type(4)));
typedef float f32x4 __attribute__((ext_vector_type(4)));   // MFMA acc

// fp32 -> bf16 (RNE) as raw short bits
static __device__ __forceinline__ short f2bf(float f) {
  unsigned u = __float_as_uint(f);
  unsigned r = (u + 0x7fff + ((u >> 16) & 1)) >> 16;
  return (short)r;
}
static __device__ __forceinline__ float bf2f(unsigned short s) {
  return __uint_as_float(((unsigned)s) << 16);
}
static __device__ __forceinline__ s16x8 pack8(const float4 a, const float4 b) {
  s16x8 r;
  r[0] = f2bf(a.x); r[1] = f2bf(a.y); r[2] = f2bf(a.z); r[3] = f2bf(a.w);
  r[4] = f2bf(b.x); r[5] = f2bf(b.y); r[6] = f2bf(b.z); r[7] = f2bf(b.w);
  return r;
}

// ---------------------------------------------------------------------------
__global__ __launch_bounds__(256)
void zero_f4(float4* __restrict__ p, int n4) {
  const int i = blockIdx.x * 256 + threadIdx.x;
  if (i < n4) p[i] = make_float4(0.f, 0.f, 0.f, 0.f);
}

// ---------------------------------------------------------------------------
// Fused qk-projection + raw scores + norms, bf16 MFMA version. (unchanged R3)
// ---------------------------------------------------------------------------
__global__ __launch_bounds__(256)
void qk_scores(const float* __restrict__ x, const float* __restrict__ w_qkv,
               float* __restrict__ S, float* __restrict__ norms) {
  const int bh = blockIdx.x;
  const int b = bh >> 3, h = bh & 7;
  const int n0 = blockIdx.y * 64;
  const int tid = threadIdx.x;
  const int lane = tid & 63;
  const int wave = tid >> 6;
  const int l15 = lane & 15;
  const int quad = lane >> 4;
  const int wave_m = wave & 1;
  const int wave_n = wave >> 1;

  __shared__ __align__(16) short smem[18432];
  short* xs  = smem;          // 64*72
  short* wsh = smem + 4608;   // 192*72
  short* qkT = smem;          // alias (phase 2)

  const int xr = tid >> 2;
  const int xc = (tid & 3) * 16;
  const float* xp = x + (size_t)(b * N_ + n0 + xr) * C_ + xc;
  const float* wp[3];
  int wrow[3];
#pragma unroll
  for (int j = 0; j < 3; ++j) {
    const int id = tid + j * 256;
    const int r = id >> 2;
    wrow[j] = r;
    const int grow = (r < 96) ? (h * 96 + r) : (C_ + h * 96 + (r - 96));
    wp[j] = w_qkv + (size_t)grow * C_ + (id & 3) * 16;
  }

  f32x4 acc[2][6] = {};

  for (int k0 = 0; k0 < C_; k0 += 64) {
    float4 xv0 = *(const float4*)(xp + k0 + 0);
    float4 xv1 = *(const float4*)(xp + k0 + 4);
    float4 xv2 = *(const float4*)(xp + k0 + 8);
    float4 xv3 = *(const float4*)(xp + k0 + 12);
    float4 wv[3][4];
#pragma unroll
    for (int j = 0; j < 3; ++j)
#pragma unroll
      for (int i = 0; i < 4; ++i)
        wv[j][i] = *(const float4*)(wp[j] + k0 + i * 4);
    __syncthreads();
    *(s16x8*)&xs[xr * 72 + xc]     = pack8(xv0, xv1);
    *(s16x8*)&xs[xr * 72 + xc + 8] = pack8(xv2, xv3);
#pragma unroll
    for (int j = 0; j < 3; ++j) {
      const int id = tid + j * 256;
      const int seg = (id & 3) * 16;
      *(s16x8*)&wsh[wrow[j] * 72 + seg]     = pack8(wv[j][0], wv[j][1]);
      *(s16x8*)&wsh[wrow[j] * 72 + seg + 8] = pack8(wv[j][2], wv[j][3]);
    }
    __syncthreads();
#pragma unroll
    for (int ks = 0; ks < 64; ks += 32) {
      s16x8 af[2];
#pragma unroll
      for (int mi = 0; mi < 2; ++mi)
        af[mi] = *(const s16x8*)&xs[(wave_m * 32 + mi * 16 + l15) * 72 + ks + quad * 8];
#pragma unroll
      for (int ni = 0; ni < 6; ++ni) {
        const s16x8 bf = *(const s16x8*)&wsh[(wave_n * 96 + ni * 16 + l15) * 72 + ks + quad * 8];
#pragma unroll
        for (int mi = 0; mi < 2; ++mi)
          acc[mi][ni] = __builtin_amdgcn_mfma_f32_16x16x32_bf16(af[mi], bf, acc[mi][ni], 0, 0, 0);
      }
    }
  }

  __syncthreads();
#pragma unroll
  for (int mi = 0; mi < 2; ++mi)
#pragma unroll
    for (int ni = 0; ni < 6; ++ni) {
      const int ch = wave_n * 96 + ni * 16 + l15;
      const int tok = wave_m * 32 + mi * 16 + quad * 4;
#pragma unroll
      for (int r = 0; r < 4; ++r)
        qkT[ch * 72 + tok + r] = f2bf(acc[mi][ni][r]);
    }
  __syncthreads();

  if (tid < 192) {
    float s = 0.f;
    const short* row = &qkT[tid * 72];
#pragma unroll 8
    for (int t = 0; t < 64; ++t) { const float v = bf2f((unsigned short)row[t]); s += v * v; }
    if (tid < 96) atomicAdd(&norms[bh * 96 + tid], s);
    else atomicAdd(&norms[B_ * H_ * 96 + bh * 96 + (tid - 96)], s);
  }

  float* Sb = S + (size_t)bh * (HD_ * HD_);
#pragma unroll
  for (int j = 0; j < 9; ++j) {
    const int t = wave * 9 + j;
    const int dt = t / 6, et = t % 6;
    f32x4 sc = {};
#pragma unroll
    for (int ks = 0; ks < 64; ks += 32) {
      const s16x8 a = *(const s16x8*)&qkT[(dt * 16 + l15) * 72 + ks + quad * 8];
      const s16x8 bb = *(const s16x8*)&qkT[(96 + et * 16 + l15) * 72 + ks + quad * 8];
      sc = __builtin_amdgcn_mfma_f32_16x16x32_bf16(a, bb, sc, 0, 0, 0);
    }
    const int d0 = dt * 16 + quad * 4;
    const int e = et * 16 + l15;
#pragma unroll
    for (int r = 0; r < 4; ++r)
      atomicAdd(&Sb[(d0 + r) * HD_ + e], sc[r]);
  }
}

// ---------------------------------------------------------------------------
// softmax over e with l2-norm scaling and temperature. One wave per row.
// ---------------------------------------------------------------------------
__global__ __launch_bounds__(256)
void softmax_rows(float* __restrict__ S, const float* __restrict__ norms,
                  const float* __restrict__ temp) {
  const int row = blockIdx.x * 4 + (threadIdx.x >> 6);
  const int lane = threadIdx.x & 63;
  const int bh = row / 96;
  const int h = bh & 7;
  const float sq = 1.0f / fmaxf(sqrtf(norms[row]), EPSN);
  const float t = temp[h];
  const float* nkb = norms + B_ * H_ * 96 + bh * 96;
  float* r = S + (size_t)row * 96;
  const float f = sq * t;
  float v0 = r[lane] * f / fmaxf(sqrtf(nkb[lane]), EPSN);
  float v1 = -1e30f;
  if (lane < 32) v1 = r[64 + lane] * f / fmaxf(sqrtf(nkb[64 + lane]), EPSN);
  float m = fmaxf(v0, v1);
#pragma unroll
  for (int o = 32; o > 0; o >>= 1) m = fmaxf(m, __shfl_xor(m, o));
  const float e0 = __expf(v0 - m);
  const float e1 = (lane < 32) ? __expf(v1 - m) : 0.0f;
  float s = e0 + e1;
#pragma unroll
  for (int o = 32; o > 0; o >>= 1) s += __shfl_xor(s, o);
  const float inv = 1.0f / s;
  r[lane] = e0 * inv;
  if (lane < 32) r[64 + lane] = e1 * inv;
}

// ---------------------------------------------------------------------------
// AV_b[h*96+d][c] = sum_e attn[bh][d][e] * w_qkv[2C + h*96 + e][c]
// ---------------------------------------------------------------------------
__global__ __launch_bounds__(256)
void av_gemm(const float* __restrict__ S, const float* __restrict__ w_qkv,
             float* __restrict__ AV) {
  const int bh = blockIdx.x;
  const int b = bh >> 3, h = bh & 7;
  const int ct = blockIdx.y * 64;
  const int tid = threadIdx.x;
  __shared__ float at[96 * 97];
  __shared__ float wv[96 * 64];
  const float* Sb = S + (size_t)bh * (HD_ * HD_);
  for (int i = tid; i < 96 * 96; i += 256)
    at[(i / 96) * 97 + (i % 96)] = Sb[i];
  for (int i = tid; i < 96 * 64; i += 256) {
    const int e = i >> 6, c = i & 63;
    wv[e * 64 + c] = w_qkv[(size_t)(2 * C_ + h * 96 + e) * C_ + ct + c];
  }
  __syncthreads();
  const int d0 = (tid >> 4) * 6;
  const int c0 = (tid & 15) * 4;
  float acc[6][4] = {};
  for (int e = 0; e < 96; ++e) {
    const float4 bv = *(const float4*)&wv[e * 64 + c0];
    float aa[6];
#pragma unroll
    for (int i = 0; i < 6; ++i) aa[i] = at[(d0 + i) * 97 + e];
#pragma unroll
    for (int i = 0; i < 6; ++i) {
      acc[i][0] += aa[i] * bv.x; acc[i][1] += aa[i] * bv.y;
      acc[i][2] += aa[i] * bv.z; acc[i][3] += aa[i] * bv.w;
    }
  }
  float* AVb = AV + (size_t)b * C_ * C_;
#pragma unroll
  for (int i = 0; i < 6; ++i)
    *(float4*)&AVb[(size_t)(h * 96 + d0 + i) * C_ + ct + c0] =
        make_float4(acc[i][0], acc[i][1], acc[i][2], acc[i][3]);
}

// ---------------------------------------------------------------------------
// NN GEMM: Mb[m][n] (bf16) = sum_k w_proj[m][k] * AV[k][n]. 64x64 tile BK=16.
// ---------------------------------------------------------------------------
__global__ __launch_bounds__(256)
void gemm_nn(const float* __restrict__ A, const float* __restrict__ B,
             short* __restrict__ Cb, int M, int N, int K,
             size_t sA, size_t sB, size_t sC) {
  const int z = blockIdx.z;
  A += z * sA; B += z * sB; Cb += z * sC;
  __shared__ float As[16 * 64];
  __shared__ float Bs[16 * 64];
  const int tid = threadIdx.x;
  const int bm = blockIdx.y * 64;
  const int bn = blockIdx.x * 64;
  const int tx = tid & 15;
  const int ty = tid >> 4;
  const int lr = tid >> 2;
  const int lk = (tid & 3) * 4;
  const int bkr = tid >> 4;
  const int bnc = (tid & 15) * 4;
  float acc[4][4] = {};
  for (int k0 = 0; k0 < K; k0 += 16) {
    const float4 av = *(const float4*)(A + (size_t)(bm + lr) * K + k0 + lk);
    const float4 bv = *(const float4*)(B + (size_t)(k0 + bkr) * N + bn + bnc);
    __syncthreads();
#pragma unroll
    for (int i = 0; i < 4; ++i) As[(lk + i) * 64 + lr] = ((const float*)&av)[i];
    *(float4*)&Bs[bkr * 64 + bnc] = bv;
    __syncthreads();
#pragma unroll
    for (int k = 0; k < 16; ++k) {
      const float4 a = *(const float4*)&As[k * 64 + ty * 4];
      const float4 b = *(const float4*)&Bs[k * 64 + tx * 4];
      acc[0][0] += a.x*b.x; acc[0][1] += a.x*b.y; acc[0][2] += a.x*b.z; acc[0][3] += a.x*b.w;
      acc[1][0] += a.y*b.x; acc[1][1] += a.y*b.y; acc[1][2] += a.y*b.z; acc[1][3] += a.y*b.w;
      acc[2][0] += a.z*b.x; acc[2][1] += a.z*b.y; acc[2][2] += a.z*b.z; acc[2][3] += a.z*b.w;
      acc[3][0] += a.w*b.x; acc[3][1] += a.w*b.y; acc[3][2] += a.w*b.z; acc[3][3] += a.w*b.w;
    }
  }
#pragma unroll
  for (int i = 0; i < 4; ++i) {
    s16x4 r;
    r[0] = f2bf(acc[i][0]); r[1] = f2bf(acc[i][1]);
    r[2] = f2bf(acc[i][2]); r[3] = f2bf(acc[i][3]);
    *(s16x4*)&Cb[(size_t)(bm + ty * 4 + i) * N + bn + tx * 4] = r;
  }
}

// ---------------------------------------------------------------------------
// Final GEMM via bf16 MFMA: out[z][m][n] = sum_k x[z][m][k]*Mb[z][n][k] + bias[n]
// 128x128 tile, BK=32, 4 waves (2x2), 4x4 16x16x32 tiles/wave.
// A: fp32 x converted on stage; B: bf16 Mb vector-loaded. LDS stride 40 shorts
// (80 B) -> 2-way bank aliasing only.
// ---------------------------------------------------------------------------
__global__ __launch_bounds__(256)
void gemm_xm(const float* __restrict__ x, const short* __restrict__ Mb,
             const float* __restrict__ bias, float* __restrict__ out) {
  const int z = blockIdx.z;
  const int n0 = blockIdx.x * 128;
  const int m0 = blockIdx.y * 128;
  const int tid = threadIdx.x;
  const int lane = tid & 63;
  const int wave = tid >> 6;
  const int l15 = lane & 15;
  const int quad = lane >> 4;
  const int wm = wave & 1;
  const int wn = wave >> 1;

  __shared__ __align__(16) short As[128 * 40];
  __shared__ __align__(16) short Bs[128 * 40];

  const int ar = tid >> 1;              // row 0..127
  const int ak = (tid & 1) * 16;        // k offset 0/16
  const float* xp = x + ((size_t)z * N_ + m0 + ar) * C_ + ak;
  const short* mp = Mb + (size_t)z * C_ * C_ + (size_t)(n0 + ar) * C_ + ak;

  f32x4 acc[4][4] = {};

  for (int k0 = 0; k0 < C_; k0 += 32) {
    const float4 a0 = *(const float4*)(xp + k0 + 0);
    const float4 a1 = *(const float4*)(xp + k0 + 4);
    const float4 a2 = *(const float4*)(xp + k0 + 8);
    const float4 a3 = *(const float4*)(xp + k0 + 12);
    const s16x8 b0 = *(const s16x8*)(mp + k0 + 0);
    const s16x8 b1 = *(const s16x8*)(mp + k0 + 8);
    __syncthreads();
    *(s16x8*)&As[ar * 40 + ak]     = pack8(a0, a1);
    *(s16x8*)&As[ar * 40 + ak + 8] = pack8(a2, a3);
    *(s16x8*)&Bs[ar * 40 + ak]     = b0;
    *(s16x8*)&Bs[ar * 40 + ak + 8] = b1;
    __syncthreads();
    s16x8 af[4];
#pragma unroll
    for (int mi = 0; mi < 4; ++mi)
      af[mi] = *(const s16x8*)&As[(wm * 64 + mi * 16 + l15) * 40 + quad * 8];
#pragma unroll
    for (int ni = 0; ni < 4; ++ni) {
      const s16x8 bf = *(const s16x8*)&Bs[(wn * 64 + ni * 16 + l15) * 40 + quad * 8];
#pragma unroll
      for (int mi = 0; mi < 4; ++mi)
        acc[mi][ni] = __builtin_amdgcn_mfma_f32_16x16x32_bf16(af[mi], bf, acc[mi][ni], 0, 0, 0);
    }
  }

  // epilogue: C-layout col = l15 (n), row = quad*4+r (m)
  float bv[4];
#pragma unroll
  for (int ni = 0; ni < 4; ++ni) bv[ni] = bias[n0 + wn * 64 + ni * 16 + l15];
#pragma unroll
  for (int mi = 0; mi < 4; ++mi) {
    const int m = m0 + wm * 64 + mi * 16 + quad * 4;
#pragma unroll
    for (int ni = 0; ni < 4; ++ni) {
      const int n = n0 + wn * 64 + ni * 16 + l15;
      float* dst = out + ((size_t)z * N_ + m) * C_ + n;
#pragma unroll
      for (int r = 0; r < 4; ++r)
        dst[(size_t)r * C_] = acc[mi][ni][r] + bv[ni];
    }
  }
}

// ---------------------------------------------------------------------------
extern "C" void kernel_launch(void* const* d_in, const int* in_sizes, int n_in,
                              void* d_out, int out_size, void* d_ws, size_t ws_size,
                              hipStream_t stream) {
  const float* x      = (const float*)d_in[0];
  const float* w_qkv  = (const float*)d_in[1];
  const float* temp   = (const float*)d_in[2];
  const float* w_proj = (const float*)d_in[3];
  const float* b_proj = (const float*)d_in[4];
  float* out = (float*)d_out;

  float* ws    = (float*)d_ws;
  float* S     = ws;                                       // 589824 f
  float* norms = S + (size_t)B_ * H_ * HD_ * HD_;          // 12288 f
  float* AV    = norms + 2 * B_ * H_ * HD_;                // 4718592 f
  short* Mb    = (short*)(AV + (size_t)B_ * C_ * C_);      // 4718592 bf16
  // total ~30.7 MB

  zero_f4<<<588, 256, 0, stream>>>((float4*)S, 150528);

  qk_scores<<<dim3(B_ * H_, N_ / 64), 256, 0, stream>>>(x, w_qkv, S, norms);

  softmax_rows<<<(B_ * H_ * HD_) / 4, 256, 0, stream>>>(S, norms, temp);

  av_gemm<<<dim3(B_ * H_, C_ / 64), 256, 0, stream>>>(S, w_qkv, AV);

  // Mb_z = bf16( w_proj @ AV_z )   -> stored [n][k] row-major (= M^T layout)
  gemm_nn<<<dim3(C_ / 64, C_ / 64, B_), 256, 0, stream>>>(
      w_proj, AV, Mb, C_, C_, C_, 0, (size_t)C_ * C_, (size_t)C_ * C_);

  // out[z] = x[z] @ Mb_z^T + bias  (bf16 MFMA)
  gemm_xm<<<dim3(C_ / 128, N_ / 128, B_), 256, 0, stream>>>(x, Mb, b_proj, out);
}